// Round 5
// baseline (185.776 us; speedup 1.0000x reference)
//
#include <hip/hip_runtime.h>
#include <stdint.h>

typedef __attribute__((ext_vector_type(8))) short bf16x8;
typedef __attribute__((ext_vector_type(4))) float f32x4;

#define HH  100   // history length
#define DD  128   // embedding dim d
#define HID 256   // hidden width / concat dim
#define NT  7     // m-tiles (112 rows >= 100)

__device__ __forceinline__ unsigned short f2bf(float f) {
    unsigned int u = __float_as_uint(f);
    u += 0x7fffu + ((u >> 16) & 1u);   // RNE
    return (unsigned short)(u >> 16);
}

// Pack W1 (256x256 f32, [n][k]) into MFMA fragment order, bf16 (runs once).
// unit = (st*8+s)*64 + lane holds W1[st*16 + (lane&15)][s*32 + (lane>>4)*8 + j]
__global__ void w1_pack(const float* __restrict__ W1, unsigned short* __restrict__ W1p) {
    int unit = blockIdx.x * 256 + threadIdx.x;   // 0..8191
    int lane = unit & 63;
    int s    = (unit >> 6) & 7;
    int st   = unit >> 9;
    int col  = lane & 15, quad = lane >> 4;
    const float* src = W1 + (size_t)(st * 16 + col) * HID + s * 32 + quad * 8;
    union { unsigned short u[8]; bf16x8 v; } o;
    #pragma unroll
    for (int j = 0; j < 8; j++) o.u[j] = f2bf(src[j]);
    *(bf16x8*)(W1p + (size_t)unit * 8) = o.v;
}

// pure-VALU packed bf16 convert (no memory side effects — safe asm)
__device__ __forceinline__ unsigned int cvt_pk_bf16(float lo, float hi) {
    unsigned int r;   // r[15:0]=bf16(lo), r[31:16]=bf16(hi)
    asm("v_cvt_pk_bf16_f32 %0, %1, %2" : "=v"(r) : "v"(lo), "v"(hi));
    return r;
}

// multiply 2 float4 by tgt slice, accumulate xsum, cvt+store one A-frag s-step
#define CONSUME(V0, V1, S, AP, TGT, ACC) do {                                     \
    const float* tp_ = (TGT) + (S) * 32 + quad * 8;                               \
    float4 t0_ = *(const float4*)tp_, t1_ = *(const float4*)(tp_ + 4);            \
    float x0=(V0).x*t0_.x, x1=(V0).y*t0_.y, x2=(V0).z*t0_.z, x3=(V0).w*t0_.w;     \
    float x4=(V1).x*t1_.x, x5=(V1).y*t1_.y, x6=(V1).z*t1_.z, x7=(V1).w*t1_.w;     \
    (ACC) += (x0+x1)+(x2+x3)+((x4+x5)+(x6+x7));                                   \
    union { unsigned int u[4]; int4 v; } fb_;                                     \
    fb_.u[0]=cvt_pk_bf16(x0,x1); fb_.u[1]=cvt_pk_bf16(x2,x3);                     \
    fb_.u[2]=cvt_pk_bf16(x4,x5); fb_.u[3]=cvt_pk_bf16(x6,x7);                     \
    *(int4*)((AP) + (size_t)((S) * 64 + lane) * 8) = fb_.v;                       \
} while (0)

#define MFMA_PAIR(MM0, MM1) do {                                                  \
    int m0_ = (MM0); if (m0_ >= NT) m0_ -= NT;                                    \
    int m1_ = (MM1); if (m1_ >= NT) m1_ -= NT;                                    \
    const unsigned short* a0p_ = Ab + m0_ * 4096;                                 \
    const unsigned short* a1p_ = Ab + m1_ * 4096;                                 \
    f32x4 c00_={0,0,0,0}, c01_={0,0,0,0}, c10_={0,0,0,0}, c11_={0,0,0,0};         \
    _Pragma("unroll")                                                             \
    for (int s_ = 0; s_ < 8; s_++) {                                              \
        bf16x8 x0_ = *(const bf16x8*)(a0p_ + (size_t)(s_ * 64 + lane) * 8);       \
        bf16x8 x1_ = *(const bf16x8*)(a1p_ + (size_t)(s_ * 64 + lane) * 8);       \
        c00_ = __builtin_amdgcn_mfma_f32_16x16x32_bf16(w1f[s_],     x0_, c00_, 0,0,0); \
        c01_ = __builtin_amdgcn_mfma_f32_16x16x32_bf16(w1f[8 + s_], x0_, c01_, 0,0,0); \
        c10_ = __builtin_amdgcn_mfma_f32_16x16x32_bf16(w1f[s_],     x1_, c10_, 0,0,0); \
        c11_ = __builtin_amdgcn_mfma_f32_16x16x32_bf16(w1f[8 + s_], x1_, c11_, 0,0,0); \
    }                                                                             \
    float sp0_ = 0.f, sp1_ = 0.f;                                                 \
    _Pragma("unroll")                                                             \
    for (int r_ = 0; r_ < 4; r_++) {                                              \
        float z00_=c00_[r_]+bb0[r_], z01_=c01_[r_]+bb1[r_];                       \
        float z10_=c10_[r_]+bb0[r_], z11_=c11_[r_]+bb1[r_];                       \
        sp0_ += ((z00_>0.f)?z00_*ww0[r_]:0.f) + ((z01_>0.f)?z01_*ww1[r_]:0.f);    \
        sp1_ += ((z10_>0.f)?z10_*ww0[r_]:0.f) + ((z11_>0.f)?z11_*ww1[r_]:0.f);    \
    }                                                                             \
    sp0_ += __shfl_xor(sp0_, 16); sp0_ += __shfl_xor(sp0_, 32);                   \
    sp1_ += __shfl_xor(sp1_, 16); sp1_ += __shfl_xor(sp1_, 32);                   \
    if (quad == 0) {                                                              \
        scorep[wave][m0_ * 16 + col] = sp0_;                                      \
        scorep[wave][m1_ * 16 + col] = sp1_;                                      \
    }                                                                             \
} while (0)

#define MFMA_SINGLE(MM0) do {                                                     \
    int m0_ = (MM0); if (m0_ >= NT) m0_ -= NT;                                    \
    const unsigned short* a0p_ = Ab + m0_ * 4096;                                 \
    f32x4 c00_={0,0,0,0}, c01_={0,0,0,0};                                         \
    _Pragma("unroll")                                                             \
    for (int s_ = 0; s_ < 8; s_++) {                                              \
        bf16x8 x0_ = *(const bf16x8*)(a0p_ + (size_t)(s_ * 64 + lane) * 8);       \
        c00_ = __builtin_amdgcn_mfma_f32_16x16x32_bf16(w1f[s_],     x0_, c00_, 0,0,0); \
        c01_ = __builtin_amdgcn_mfma_f32_16x16x32_bf16(w1f[8 + s_], x0_, c01_, 0,0,0); \
    }                                                                             \
    float sp0_ = 0.f;                                                             \
    _Pragma("unroll")                                                             \
    for (int r_ = 0; r_ < 4; r_++) {                                              \
        float z00_=c00_[r_]+bb0[r_], z01_=c01_[r_]+bb1[r_];                       \
        sp0_ += ((z00_>0.f)?z00_*ww0[r_]:0.f) + ((z01_>0.f)?z01_*ww1[r_]:0.f);    \
    }                                                                             \
    sp0_ += __shfl_xor(sp0_, 16); sp0_ += __shfl_xor(sp0_, 32);                   \
    if (quad == 0) scorep[wave][m0_ * 16 + col] = sp0_;                           \
} while (0)

// Persistent pipelined blocks, 1 block/CU, NB elements each. W1 frags loaded once
// per block (pinned). Next-element gather loads are PLAIN C++ loads issued in the
// same region as the MFMA sweep (scheduler hoists them; __syncthreads' fences stop
// them sinking into the consume phase) — compiler owns all waitcnt bookkeeping, so
// spills are slow-but-correct. Rounds 3/4's asm in-flight loads faulted on spill.
__global__ __launch_bounds__(512, 2) void nais_kernel(
    const int* __restrict__ history,           // [B,HH]
    const int* __restrict__ target,            // [B]
    const int* __restrict__ history_region,    // [B,HH]
    const int* __restrict__ target_region,     // [B]
    const float* __restrict__ target_distance, // [B]
    const float* __restrict__ E_hist,          // [item,128]
    const float* __restrict__ E_tgt,           // [item,128]
    const float* __restrict__ E_reg,           // [region,128]
    const float* __restrict__ E_dist,          // [16,128]
    const float* __restrict__ b1,              // [256]
    const float* __restrict__ w2,              // [256]
    const unsigned short* __restrict__ W1p,    // packed bf16 fragments (128 KB)
    float* __restrict__ out,                   // [B]
    int Btot)
{
    __shared__ __align__(16) unsigned short As[2][NT * 4096];  // 112 KB
    __shared__ __align__(16) float tgts3[3][HID];
    __shared__ __align__(16) float b1s[HID];
    __shared__ __align__(16) float w2s[HID];
    __shared__ __align__(16) int   hidx3[3][HH];
    __shared__ __align__(16) int   hreg3[3][HH];
    __shared__ __align__(16) float scorep[8][112];
    __shared__ __align__(16) float xsum2[2][112];
    __shared__ int   tgA[64];
    __shared__ int   trA[64];
    __shared__ float tdA[64];
    __shared__ float p12[2][4];
    __shared__ float s_sumE;

    const int t    = threadIdx.x;
    const int lane = t & 63;
    const int wave = t >> 6;
    const int col  = lane & 15;
    const int quad = lane >> 4;

    const int NB   = (Btot + gridDim.x - 1) / gridDim.x;
    const int base = blockIdx.x * NB;
    int cnt = Btot - base;
    if (cnt <= 0) return;
    if (cnt > NB) cnt = NB;

    // ---- prologue: scalars ----
    if (t < cnt) {
        tgA[t] = target[base + t];
        trA[t] = target_region[base + t];
        tdA[t] = target_distance[base + t];
    }
    if (wave == 4) {
        *(float4*)(b1s + lane * 4) = *(const float4*)(b1 + lane * 4);
        *(float4*)(w2s + lane * 4) = *(const float4*)(w2 + lane * 4);
    }
    if (wave == 5) {
        float v = E_dist[lane] + E_dist[64 + lane];
        #pragma unroll
        for (int off = 32; off; off >>= 1) v += __shfl_xor(v, off);
        if (lane == 0) s_sumE = v;
    }
    __syncthreads();   // P1

    // ---- W1 fragments -> registers, once per block, pinned ----
    bf16x8 w1f[16];
    #pragma unroll
    for (int i = 0; i < 16; i++) {
        const int unit = ((2 * wave + (i >> 3)) * 8 + (i & 7)) * 64 + lane;
        w1f[i] = *(const bf16x8*)(W1p + (size_t)unit * 8);
    }
    #pragma unroll
    for (int i = 0; i < 16; i++) asm volatile("" : "+v"(w1f[i]));

    // ---- prologue: meta for e0 (slot 0) and e1 (slot 1) ----
    if (wave < 2 && wave < cnt) {
        const int em = base + wave;
        int4 mh = {0,0,0,0}, mr = {0,0,0,0};
        if (lane < 25)      mh = *(const int4*)(history + (size_t)em * HH + lane * 4);
        else if (lane < 50) mr = *(const int4*)(history_region + (size_t)em * HH + (lane - 25) * 4);
        const int tg2 = tgA[wave], tr2 = trA[wave];
        const float* tp2 = (lane < 32) ? (E_tgt + (size_t)tg2 * DD + lane * 4)
                                       : (E_reg + (size_t)tr2 * DD + (lane - 32) * 4);
        float4 mt4 = *(const float4*)tp2;
        if (lane < 25)      *(int4*)&hidx3[wave][lane * 4] = mh;
        else if (lane < 50) *(int4*)&hreg3[wave][(lane - 25) * 4] = mr;
        *(float4*)&tgts3[wave][lane * 4] = mt4;
    }
    __syncthreads();   // P2

    // ---- prologue: gather e0 into As[0], xsum2[0] ----
    if (wave < NT) {
        const int row0 = wave * 16 + col;
        const int rc  = (row0 < HH) ? row0 : row0 - 64;
        const int ih  = hidx3[0][rc];
        const int ir  = hreg3[0][rc];
        const float* ph = E_hist + (size_t)ih * DD + quad * 8;
        const float* pr = E_reg  + (size_t)ir * DD + quad * 8;
        unsigned short* ap = &As[0][wave * 4096];
        float4 g[16];
        #pragma unroll
        for (int s = 0; s < 4; s++) {
            g[2*s]     = *(const float4*)(ph + s * 32);
            g[2*s + 1] = *(const float4*)(ph + s * 32 + 4);
            g[8 + 2*s] = *(const float4*)(pr + s * 32);
            g[9 + 2*s] = *(const float4*)(pr + s * 32 + 4);
        }
        float acc = 0.f;
        #pragma unroll
        for (int s = 0; s < 8; s++) CONSUME(g[2*s], g[2*s+1], s, ap, tgts3[0], acc);
        float v = acc;
        v += __shfl_xor(v, 16);
        v += __shfl_xor(v, 32);
        if (quad == 0) xsum2[0][row0] = v;
    }

    const int st0 = 2 * wave;
    const f32x4 bb0 = *(const f32x4*)&b1s[st0 * 16 + quad * 4];
    const f32x4 bb1 = *(const f32x4*)&b1s[st0 * 16 + 16 + quad * 4];
    const f32x4 ww0 = *(const f32x4*)&w2s[st0 * 16 + quad * 4];
    const f32x4 ww1 = *(const f32x4*)&w2s[st0 * 16 + 16 + quad * 4];

    __syncthreads();   // P3 (= B1 for i=0)

    int cur = 0, cm = 0, nm = 1, n2 = 2;

    #pragma unroll 1
    for (int i = 0; i < cnt; i++) {
        const bool do_g = (i + 1 < cnt) && (wave < NT);
        const bool do_m = (i + 2 < cnt) && (wave == 7);

        // ---- AB region: issue next-element loads, then MFMA sweep (one region;
        //      scheduler hoists the independent loads above/among the MFMAs) ----
        float4 g[16];
        int row0 = 0;
        if (do_g) {
            row0 = wave * 16 + col;
            const int rc = (row0 < HH) ? row0 : row0 - 64;
            const int ih = hidx3[nm][rc];
            const int ir = hreg3[nm][rc];
            const float* ph = E_hist + (size_t)ih * DD + quad * 8;
            const float* pr = E_reg  + (size_t)ir * DD + quad * 8;
            #pragma unroll
            for (int s = 0; s < 4; s++) {
                g[2*s]     = *(const float4*)(ph + s * 32);
                g[2*s + 1] = *(const float4*)(ph + s * 32 + 4);
                g[8 + 2*s] = *(const float4*)(pr + s * 32);
                g[9 + 2*s] = *(const float4*)(pr + s * 32 + 4);
            }
        }
        int4 mh = {0,0,0,0}, mr4 = {0,0,0,0};
        float4 mt4 = {0.f, 0.f, 0.f, 0.f};
        if (do_m) {
            const int em = base + i + 2;
            if (lane < 25)      mh  = *(const int4*)(history + (size_t)em * HH + lane * 4);
            else if (lane < 50) mr4 = *(const int4*)(history_region + (size_t)em * HH + (lane - 25) * 4);
            const int tg2 = tgA[i + 2], tr2 = trA[i + 2];
            const float* tp2 = (lane < 32) ? (E_tgt + (size_t)tg2 * DD + lane * 4)
                                           : (E_reg + (size_t)tr2 * DD + (lane - 32) * 4);
            mt4 = *(const float4*)tp2;
        }

        const unsigned short* Ab = &As[cur][0];

        MFMA_PAIR(wave,     wave + 1);
        MFMA_PAIR(wave + 2, wave + 3);
        MFMA_PAIR(wave + 4, wave + 5);
        MFMA_SINGLE(wave + 6);

        __syncthreads();   // B2

        // ---- D: softmax partials for e=i; deferred finish of e-1 ----
        {
            float sc = 0.f;
            if (t < 112) {
                #pragma unroll
                for (int w = 0; w < 8; w++) sc += scorep[w][t];
            }
            float e1v = 0.f, e2v = 0.f;
            if (t < HH) {
                const float dist = tdA[i] * s_sumE;
                if (hidx3[cm][t] != tgA[i]) {
                    float e = expf(sc + dist);
                    e1v = e;
                    e2v = e * xsum2[cur][t];
                }
            }
            if (wave < 2) {
                #pragma unroll
                for (int off = 32; off; off >>= 1) {
                    e1v += __shfl_xor(e1v, off);
                    e2v += __shfl_xor(e2v, off);
                }
                if (lane == 0) {
                    p12[cur][wave]     = e1v;
                    p12[cur][2 + wave] = e2v;
                }
            }
            if (i > 0 && t == 128) {     // wave 2 lane 0 finishes e-1
                float s1 = p12[cur ^ 1][0] + p12[cur ^ 1][1];
                float s2 = p12[cur ^ 1][2] + p12[cur ^ 1][3];
                float pred = s2 / sqrtf(s1);   // denom^BETA, BETA=0.5
                out[base + i - 1] = 1.f / (1.f + expf(-pred));
            }
        }

        // ---- E: consume prefetched loads -> As[cur^1], xsum; wave7 meta store ----
        if (do_g) {
            unsigned short* An = &As[cur ^ 1][wave * 4096];
            const float* tgt = &tgts3[nm][0];
            float acc = 0.f;
            #pragma unroll
            for (int s = 0; s < 8; s++) CONSUME(g[2*s], g[2*s+1], s, An, tgt, acc);
            float v = acc;
            v += __shfl_xor(v, 16);
            v += __shfl_xor(v, 32);
            if (quad == 0) xsum2[cur ^ 1][row0] = v;
        } else if (do_m) {
            if (lane < 25)      *(int4*)&hidx3[n2][lane * 4] = mh;
            else if (lane < 50) *(int4*)&hreg3[n2][(lane - 25) * 4] = mr4;
            *(float4*)&tgts3[n2][lane * 4] = mt4;
        }

        __syncthreads();   // B1
        cur ^= 1;
        const int tmp = cm; cm = nm; nm = n2; n2 = tmp;
    }

    // ---- final element finish ----
    if (t == 0) {
        const int sl = (cnt - 1) & 1;
        float s1 = p12[sl][0] + p12[sl][1];
        float s2 = p12[sl][2] + p12[sl][3];
        float pred = s2 / sqrtf(s1);
        out[base + cnt - 1] = 1.f / (1.f + expf(-pred));
    }
}

extern "C" void kernel_launch(void* const* d_in, const int* in_sizes, int n_in,
                              void* d_out, int out_size, void* d_ws, size_t ws_size,
                              hipStream_t stream) {
    const int*   history         = (const int*)d_in[0];
    const int*   target          = (const int*)d_in[1];
    const int*   history_region  = (const int*)d_in[2];
    const int*   target_region   = (const int*)d_in[3];
    const float* target_distance = (const float*)d_in[4];
    const float* E_hist          = (const float*)d_in[5];
    const float* E_tgt           = (const float*)d_in[6];
    const float* E_reg           = (const float*)d_in[7];
    const float* E_dist          = (const float*)d_in[8];
    const float* W1              = (const float*)d_in[9];
    const float* b1              = (const float*)d_in[10];
    const float* w2              = (const float*)d_in[11];

    unsigned short* W1p = (unsigned short*)d_ws;  // 131072 B
    const int B = in_sizes[1];

    int grid = (B + 7) / 8;
    if (grid > 256) grid = 256;

    w1_pack<<<32, 256, 0, stream>>>(W1, W1p);
    nais_kernel<<<grid, 512, 0, stream>>>(history, target, history_region, target_region,
                                          target_distance, E_hist, E_tgt, E_reg, E_dist,
                                          b1, w2, W1p, (float*)d_out, B);
}